// Round 7
// baseline (144.444 us; speedup 1.0000x reference)
//
#include <hip/hip_runtime.h>

#define NPTS  65536
#define KNB   32
#define KPn   15
#define CIN   64
#define COUT  128
#define MPTS  16            // points per block (MFMA M of GEMM2)
#define THREADS 512         // 8 waves/block; 4 blocks/CU = 32 waves/CU
#define WSTRIDE 968         // wl row stride in bf16 elems (960 + 8 pad)
#define NTILE 8             // 128 cols / 16
#define KSTEPS 30           // 960 / 32
#define WELEMS (NTILE * KSTEPS * 64 * 8)    // 122880 bf16 elements

typedef __attribute__((ext_vector_type(8))) short short8;
typedef __attribute__((ext_vector_type(4))) float f32x4;

__device__ __forceinline__ unsigned int f2bf(float f) {
    union { float f; unsigned int i; } v; v.f = f;
    return (v.i + 0x7fffu + ((v.i >> 16) & 1u)) >> 16;   // RNE
}
__device__ __forceinline__ float rlanef(float v, int l) {
    union { float f; int i; } u; u.f = v;
    u.i = __builtin_amdgcn_readlane(u.i, l);
    return u.f;
}

// ---- prep: pack weights into MFMA B-fragment order (permuted K) + kpq/R2 ----
// K-enum: f = cg*120 + k*8 + j  (cg = c>>3, j = c&7)  ->  orig = k*64 + c
__global__ void wtrans_kernel(const float* __restrict__ w,
                              const float* __restrict__ kpts,
                              unsigned short* __restrict__ wTf,
                              float4* __restrict__ kpq_out) {  // [16]: 15 kpq + {R2}
    const int d = blockIdx.x * 256 + threadIdx.x;
    if (d < WELEMS) {
        const int j    = d & 7;
        const int lane = (d >> 3) & 63;
        const int ks   = (d >> 9) % KSTEPS;
        const int t    = d / (KSTEPS * 512);
        const int f    = ks * 32 + (lane >> 4) * 8 + j;
        const int cg   = f / 120;
        const int rem  = f - cg * 120;
        const int orig = (rem >> 3) * 64 + cg * 8 + (rem & 7);
        const int n    = t * 16 + (lane & 15);
        wTf[d] = (unsigned short)f2bf(w[(size_t)orig * COUT + n]);
    }
    if (blockIdx.x == 0 && threadIdx.x < 16) {
        const int k = threadIdx.x;
        if (k < KPn) {
            const float x = kpts[k * 3 + 0];
            const float y = kpts[k * 3 + 1];
            const float z = kpts[k * 3 + 2];
            kpq_out[k] = make_float4(x, y, z, x * x + y * y + z * z);
        } else {
            float mx = 0.f;
            for (int i = 0; i < KPn; ++i) {
                const float x = kpts[i * 3 + 0];
                const float y = kpts[i * 3 + 1];
                const float z = kpts[i * 3 + 2];
                mx = fmaxf(mx, x * x + y * y + z * z);
            }
            const float R = 0.1f + sqrtf(mx);
            kpq_out[15] = make_float4(R * R, 0.f, 0.f, 0.f);
        }
    }
}

// process one point-half's survivor mask; lanes = channels, ACC[k] in regs
#define PROC_HALF(MSK, ACC)                                                   \
    {                                                                         \
        unsigned long long msk_ = (MSK);                                      \
        while (msk_) {                                                        \
            const int j_ = (int)__builtin_ctzll(msk_);                        \
            msk_ &= msk_ - 1;                                                 \
            const int   nbs_ = __builtin_amdgcn_readlane(nbv, j_);            \
            const float rxs_ = rlanef(rx, j_);                                \
            const float rys_ = rlanef(ry, j_);                                \
            const float rzs_ = rlanef(rz, j_);                                \
            const float d2s_ = rlanef(d2r, j_);                               \
            const float f_   = feats[(size_t)nbs_ * CIN + lane];              \
            _Pragma("unroll")                                                 \
            for (int k = 0; k < KPn; ++k) {                                   \
                const float  dot = rxs_ * kpx[k] + rys_ * kpy[k] + rzs_ * kpz[k]; \
                if (dot > 0.5f * (d2s_ - 0.01f + kpw[k])) {                   \
                    const float dd = fmaxf(d2s_ - 2.f * dot + kpw[k], 0.f);   \
                    const float w_ = 1.0f - 10.0f * sqrtf(dd);                \
                    ACC[k] += w_ * f_;                                        \
                }                                                             \
            }                                                                 \
        }                                                                     \
    }

__global__ __launch_bounds__(THREADS, 8) void kpconv_kernel(
    const float* __restrict__ pos,         // [N,3] f32
    const float* __restrict__ feats,       // [N,64] f32
    const unsigned short* __restrict__ wTf,// fragment-packed bf16 weights
    const float4* __restrict__ kpq_in,     // [16] precomputed kpq + R2
    const int*   __restrict__ neighbors,   // [N,32] int32
    float*       __restrict__ out)         // [N,128] f32
{
    __shared__ __align__(16) unsigned short wl[MPTS * WSTRIDE];  // 30976 B

    const int tid  = threadIdx.x;
    const int n0   = blockIdx.x * MPTS;
    const int lane = tid & 63;
    const int wv   = tid >> 6;             // wave 0..7 owns points 2wv, 2wv+1
    const int m    = lane & 15;
    const int q    = lane >> 4;

    // ---- stage 1: fully wave-autonomous, zero barriers ----
    // lanes 0-31 = point A's 32 neighbor slots; lanes 32-63 = point B's
    const int nbv = neighbors[(size_t)n0 * KNB + tid];
    const float px = pos[(size_t)nbv * 3 + 0];
    const float py = pos[(size_t)nbv * 3 + 1];
    const float pz = pos[(size_t)nbv * 3 + 2];

    // uniform kernel-point constants -> SGPRs (hoisted out of survivor loop)
    float kpx[KPn], kpy[KPn], kpz[KPn], kpw[KPn];
    #pragma unroll
    for (int k = 0; k < KPn; ++k) {
        const float4 kp = kpq_in[k];
        kpx[k] = kp.x; kpy[k] = kp.y; kpz[k] = kp.z; kpw[k] = kp.w;
    }
    const float R2 = kpq_in[15].x;                                // uniform

    const int nAu = __builtin_amdgcn_readfirstlane(n0 + wv * 2);  // uniform
    const float cxA = pos[(size_t)nAu * 3 + 0];
    const float cyA = pos[(size_t)nAu * 3 + 1];
    const float czA = pos[(size_t)nAu * 3 + 2];
    const float cxB = pos[(size_t)(nAu + 1) * 3 + 0];
    const float cyB = pos[(size_t)(nAu + 1) * 3 + 1];
    const float czB = pos[(size_t)(nAu + 1) * 3 + 2];

    const bool isA = (lane < 32);
    const float rx = px - (isA ? cxA : cxB);
    const float ry = py - (isA ? cyA : cyB);
    const float rz = pz - (isA ? czA : czB);
    const float d2r = rx * rx + ry * ry + rz * rz;

    const unsigned long long bal = __ballot(d2r < R2);            // ~6% set

    float accA[KPn], accB[KPn];
    #pragma unroll
    for (int k = 0; k < KPn; ++k) { accA[k] = 0.f; accB[k] = 0.f; }

    PROC_HALF(bal & 0x00000000ffffffffull, accA);
    PROC_HALF(bal & 0xffffffff00000000ull, accB);

    // ---- pack weighted (lane = channel c) into wl, permuted-K layout ----
    {
        const int cg = lane >> 3, j = lane & 7;
        unsigned short* wpA = wl + (wv * 2 + 0) * WSTRIDE + cg * 120 + j;
        unsigned short* wpB = wl + (wv * 2 + 1) * WSTRIDE + cg * 120 + j;
        #pragma unroll
        for (int k = 0; k < KPn; ++k) {
            wpA[k * 8] = (unsigned short)f2bf(accA[k]);
            wpB[k * 8] = (unsigned short)f2bf(accB[k]);
        }
    }
    __syncthreads();   // the ONLY block barrier

    // ---- GEMM2: out[16][128] = wl[16][960] @ W; one N-tile per wave ----
    {
        f32x4 o0 = {0.f, 0.f, 0.f, 0.f};
        f32x4 o1 = {0.f, 0.f, 0.f, 0.f};
        const unsigned short* ap = wl + m * WSTRIDE + q * 8;
        const short8* bp = (const short8*)wTf + (size_t)wv * KSTEPS * 64 + lane;

        #pragma unroll 3
        for (int ks = 0; ks < KSTEPS; ks += 2) {
            const short8 a0 = *(const short8*)(ap + ks * 32);
            const short8 b0 = bp[ks * 64];
            o0 = __builtin_amdgcn_mfma_f32_16x16x32_bf16(a0, b0, o0, 0, 0, 0);
            const short8 a1 = *(const short8*)(ap + (ks + 1) * 32);
            const short8 b1 = bp[(ks + 1) * 64];
            o1 = __builtin_amdgcn_mfma_f32_16x16x32_bf16(a1, b1, o1, 0, 0, 0);
        }
        o0 = o0 + o1;

        // C/D layout: col = lane&15, row = q*4 + reg
        const int c = wv * 16 + m;
        #pragma unroll
        for (int r = 0; r < 4; ++r)
            out[(size_t)(n0 + q * 4 + r) * COUT + c] = o0[r];
    }
}

extern "C" void kernel_launch(void* const* d_in, const int* in_sizes, int n_in,
                              void* d_out, int out_size, void* d_ws, size_t ws_size,
                              hipStream_t stream) {
    const float* pos       = (const float*)d_in[0];
    const float* feats     = (const float*)d_in[1];
    const float* kpts      = (const float*)d_in[2];
    const float* weights   = (const float*)d_in[3];
    const int*   neighbors = (const int*)d_in[4];
    float*       out       = (float*)d_out;
    unsigned short* wTf    = (unsigned short*)d_ws;               // 245760 B
    float4* kpq            = (float4*)((char*)d_ws + WELEMS * 2); // 256 B

    wtrans_kernel<<<(WELEMS + 255) / 256, 256, 0, stream>>>(weights, kpts, wTf, kpq);
    kpconv_kernel<<<NPTS / MPTS, THREADS, 0, stream>>>(
        pos, feats, wTf, kpq, neighbors, out);
}

// Round 8
// 136.484 us; speedup vs baseline: 1.0583x; 1.0583x over previous
//
#include <hip/hip_runtime.h>

#define NPTS  65536
#define KNB   32
#define KPn   15
#define CIN   64
#define COUT  128
#define MPTS  16            // points per block (MFMA M of GEMM2)
#define THREADS 512         // 8 waves/block; 4 blocks/CU = 32 waves/CU
#define WSTRIDE 968         // wl row stride in bf16 elems (960 + 8 pad)
#define NTILE 8             // 128 cols / 16
#define KSTEPS 30           // 960 / 32
#define WELEMS (NTILE * KSTEPS * 64 * 8)    // 122880 bf16 elements

typedef __attribute__((ext_vector_type(8))) short short8;
typedef __attribute__((ext_vector_type(4))) float f32x4;

__device__ __forceinline__ unsigned int f2bf(float f) {
    union { float f; unsigned int i; } v; v.f = f;
    return (v.i + 0x7fffu + ((v.i >> 16) & 1u)) >> 16;   // RNE
}

// ---- prep: pack weights into MFMA B-fragment order (permuted K) + kpq/R2 ----
// K-enum: f = cg*120 + k*8 + j  (cg = c>>3, j = c&7)  ->  orig = k*64 + c
__global__ void wtrans_kernel(const float* __restrict__ w,
                              const float* __restrict__ kpts,
                              unsigned short* __restrict__ wTf,
                              float4* __restrict__ kpq_out) {  // [16]: 15 kpq + {R2}
    const int d = blockIdx.x * 256 + threadIdx.x;
    if (d < WELEMS) {
        const int j    = d & 7;
        const int lane = (d >> 3) & 63;
        const int ks   = (d >> 9) % KSTEPS;
        const int t    = d / (KSTEPS * 512);
        const int f    = ks * 32 + (lane >> 4) * 8 + j;
        const int cg   = f / 120;
        const int rem  = f - cg * 120;
        const int orig = (rem >> 3) * 64 + cg * 8 + (rem & 7);
        const int n    = t * 16 + (lane & 15);
        wTf[d] = (unsigned short)f2bf(w[(size_t)orig * COUT + n]);
    }
    if (blockIdx.x == 0 && threadIdx.x < 16) {
        const int k = threadIdx.x;
        if (k < KPn) {
            const float x = kpts[k * 3 + 0];
            const float y = kpts[k * 3 + 1];
            const float z = kpts[k * 3 + 2];
            kpq_out[k] = make_float4(x, y, z, x * x + y * y + z * z);
        } else {
            float mx = 0.f;
            for (int i = 0; i < KPn; ++i) {
                const float x = kpts[i * 3 + 0];
                const float y = kpts[i * 3 + 1];
                const float z = kpts[i * 3 + 2];
                mx = fmaxf(mx, x * x + y * y + z * z);
            }
            const float R = 0.1f + sqrtf(mx);
            kpq_out[15] = make_float4(R * R, 0.f, 0.f, 0.f);
        }
    }
}

// accumulate one point-half for static k: walk survivor bits, coalesced feats
#define ACC_HALF(MHALF, BASE, ACCV)                                           \
    {                                                                         \
        unsigned long long mh_ = (MHALF);                                     \
        while (mh_) {                                                         \
            const int j_ = (int)__builtin_ctzll(mh_) + (BASE);                \
            mh_ &= mh_ - 1;                                                   \
            const int nb_ = __builtin_amdgcn_readlane(nbv, j_);               \
            const unsigned int wp_ =                                          \
                (unsigned int)__builtin_amdgcn_readlane((int)wpk[k >> 1], j_);\
            const float w_ = (float)((wp_ >> (16 * (k & 1))) & 0xFFFFu) *     \
                             (1.0f / 65535.0f);                               \
            ACCV += w_ * feats[(size_t)nb_ * CIN + lane];                     \
        }                                                                     \
    }

__global__ __launch_bounds__(THREADS, 8) void kpconv_kernel(
    const float* __restrict__ pos,         // [N,3] f32
    const float* __restrict__ feats,       // [N,64] f32
    const unsigned short* __restrict__ wTf,// fragment-packed bf16 weights
    const float4* __restrict__ kpq_in,     // [16] precomputed kpq + R2
    const int*   __restrict__ neighbors,   // [N,32] int32
    float*       __restrict__ out)         // [N,128] f32
{
    __shared__ __align__(16) unsigned short wl[MPTS * WSTRIDE];  // 30976 B

    const int tid  = threadIdx.x;
    const int n0   = blockIdx.x * MPTS;
    const int lane = tid & 63;
    const int wv   = tid >> 6;             // wave 0..7 owns points 2wv, 2wv+1
    const int m    = lane & 15;
    const int q    = lane >> 4;

    // ---- stage 1: wave-autonomous; lanes = 64 neighbor slots (2 points) ----
    const int nbv = neighbors[(size_t)n0 * KNB + tid];
    const float px = pos[(size_t)nbv * 3 + 0];
    const float py = pos[(size_t)nbv * 3 + 1];
    const float pz = pos[(size_t)nbv * 3 + 2];

    const int nAu = __builtin_amdgcn_readfirstlane(n0 + wv * 2);  // uniform
    const float cxA = pos[(size_t)nAu * 3 + 0];
    const float cyA = pos[(size_t)nAu * 3 + 1];
    const float czA = pos[(size_t)nAu * 3 + 2];
    const float cxB = pos[(size_t)(nAu + 1) * 3 + 0];
    const float cyB = pos[(size_t)(nAu + 1) * 3 + 1];
    const float czB = pos[(size_t)(nAu + 1) * 3 + 2];

    const bool isA = (lane < 32);
    const float rx = px - (isA ? cxA : cxB);
    const float ry = py - (isA ? cyA : cyB);
    const float rz = pz - (isA ? czA : czB);
    const float d2r = rx * rx + ry * ry + rz * rz;

    // ---- per-lane parallel kp tests: kmask + u16 weights (no prefilter) ----
    unsigned int kmask = 0;
    unsigned int wpk[8] = {0u, 0u, 0u, 0u, 0u, 0u, 0u, 0u};
    #pragma unroll
    for (int k = 0; k < KPn; ++k) {
        const float4 kp  = kpq_in[k];
        const float  dot = rx * kp.x + ry * kp.y + rz * kp.z;
        if (dot > 0.5f * (d2r - 0.01f + kp.w)) {        // dist(kp) < 0.1
            const float dd = fmaxf(d2r - 2.f * dot + kp.w, 0.f);
            const float w  = 1.0f - 10.0f * sqrtf(dd);
            const unsigned int w16 = (unsigned int)(w * 65535.0f + 0.5f);
            wpk[k >> 1] |= w16 << (16 * (k & 1));
            kmask |= 1u << k;
        }
    }

    // ---- per-k static accumulate (scalar acc, ballot-driven) -> wl ----
    {
        const int cg = lane >> 3, j8 = lane & 7;
        unsigned short* const wpA = wl + (wv * 2 + 0) * WSTRIDE + cg * 120 + j8;
        unsigned short* const wpB = wl + (wv * 2 + 1) * WSTRIDE + cg * 120 + j8;
        #pragma unroll
        for (int k = 0; k < KPn; ++k) {
            const unsigned long long mk = __ballot((kmask >> k) & 1u);
            float aA = 0.f, aB = 0.f;
            ACC_HALF(mk & 0x00000000ffffffffull, 0, aA);
            ACC_HALF(mk >> 32, 32, aB);
            wpA[k * 8] = (unsigned short)f2bf(aA);
            wpB[k * 8] = (unsigned short)f2bf(aB);
        }
    }
    __syncthreads();   // the ONLY block barrier

    // ---- GEMM2: out[16][128] = wl[16][960] @ W; one N-tile per wave ----
    {
        f32x4 o0 = {0.f, 0.f, 0.f, 0.f};
        f32x4 o1 = {0.f, 0.f, 0.f, 0.f};
        const unsigned short* ap = wl + m * WSTRIDE + q * 8;
        const short8* bp = (const short8*)wTf + (size_t)wv * KSTEPS * 64 + lane;

        #pragma unroll 3
        for (int ks = 0; ks < KSTEPS; ks += 2) {
            const short8 a0 = *(const short8*)(ap + ks * 32);
            const short8 b0 = bp[ks * 64];
            o0 = __builtin_amdgcn_mfma_f32_16x16x32_bf16(a0, b0, o0, 0, 0, 0);
            const short8 a1 = *(const short8*)(ap + (ks + 1) * 32);
            const short8 b1 = bp[(ks + 1) * 64];
            o1 = __builtin_amdgcn_mfma_f32_16x16x32_bf16(a1, b1, o1, 0, 0, 0);
        }
        o0 = o0 + o1;

        // C/D layout: col = lane&15, row = q*4 + reg
        const int c = wv * 16 + m;
        #pragma unroll
        for (int r = 0; r < 4; ++r)
            out[(size_t)(n0 + q * 4 + r) * COUT + c] = o0[r];
    }
}

extern "C" void kernel_launch(void* const* d_in, const int* in_sizes, int n_in,
                              void* d_out, int out_size, void* d_ws, size_t ws_size,
                              hipStream_t stream) {
    const float* pos       = (const float*)d_in[0];
    const float* feats     = (const float*)d_in[1];
    const float* kpts      = (const float*)d_in[2];
    const float* weights   = (const float*)d_in[3];
    const int*   neighbors = (const int*)d_in[4];
    float*       out       = (float*)d_out;
    unsigned short* wTf    = (unsigned short*)d_ws;               // 245760 B
    float4* kpq            = (float4*)((char*)d_ws + WELEMS * 2); // 256 B

    wtrans_kernel<<<(WELEMS + 255) / 256, 256, 0, stream>>>(weights, kpts, wTf, kpq);
    kpconv_kernel<<<NPTS / MPTS, THREADS, 0, stream>>>(
        pos, feats, wTf, kpq, neighbors, out);
}